// Round 4
// baseline (2568.562 us; speedup 1.0000x reference)
//
#include <hip/hip_runtime.h>
#include <math.h>

// Problem constants (fixed by the reference)
#define NN 10000
#define EE 160000
#define FF 128
#define RR 20
#define LL 3
#define CUTOFF 3.0f
#define F3 384           // 3*F
#define PI_F 3.14159265358979323846f

// ---------------------------------------------------------------------------
__device__ __forceinline__ void fma16(float acc[16], float a,
                                      float4 x0, float4 x1, float4 x2, float4 x3) {
    acc[0]  += a * x0.x; acc[1]  += a * x0.y; acc[2]  += a * x0.z; acc[3]  += a * x0.w;
    acc[4]  += a * x1.x; acc[5]  += a * x1.y; acc[6]  += a * x1.z; acc[7]  += a * x1.w;
    acc[8]  += a * x2.x; acc[9]  += a * x2.y; acc[10] += a * x2.z; acc[11] += a * x2.w;
    acc[12] += a * x3.x; acc[13] += a * x3.y; acc[14] += a * x3.z; acc[15] += a * x3.w;
}

// ---------------------------------------------------------------------------
// init: sfeat = emb[z], v = 0, deg = 0
__global__ __launch_bounds__(256) void k_init(const int* __restrict__ z,
                                              const float* __restrict__ emb,
                                              float* __restrict__ sfeat,
                                              float* __restrict__ v,
                                              int* __restrict__ deg) {
    int idx = blockIdx.x * 256 + threadIdx.x;
    if (idx < NN * 3 * FF) v[idx] = 0.f;
    if (idx < NN * FF) {
        int n = idx >> 7, f = idx & 127;
        sfeat[idx] = emb[z[n] * FF + f];
    }
    if (idx < NN) deg[idx] = 0;
}

// ---------------------------------------------------------------------------
// CSR build: count, exclusive-scan (single block), fill
__global__ __launch_bounds__(256) void k_count(const int* __restrict__ idx_i,
                                               int* __restrict__ deg) {
    int e = blockIdx.x * 256 + threadIdx.x;
    if (e < EE) atomicAdd(&deg[idx_i[e]], 1);
}

__global__ __launch_bounds__(1024) void k_scan(const int* __restrict__ deg,
                                               int* __restrict__ rowstart,
                                               int* __restrict__ cursor) {
    __shared__ int sd[1024];
    __shared__ int carry;
    if (threadIdx.x == 0) carry = 0;
    __syncthreads();
    for (int base = 0; base < NN; base += 1024) {
        int i = base + (int)threadIdx.x;
        int val = (i < NN) ? deg[i] : 0;
        sd[threadIdx.x] = val;
        __syncthreads();
        for (int off = 1; off < 1024; off <<= 1) {
            int t = (threadIdx.x >= off) ? sd[threadIdx.x - off] : 0;
            __syncthreads();
            sd[threadIdx.x] += t;
            __syncthreads();
        }
        if (i < NN) {
            int ex = carry + sd[threadIdx.x] - val;   // exclusive prefix
            rowstart[i] = ex;
            cursor[i] = ex;
        }
        __syncthreads();
        if (threadIdx.x == 0) carry += sd[1023];
        __syncthreads();
    }
    if (threadIdx.x == 0) rowstart[NN] = carry;
}

__global__ __launch_bounds__(256) void k_fill(const int* __restrict__ idx_i,
                                              int* __restrict__ cursor,
                                              int* __restrict__ eids) {
    int e = blockIdx.x * 256 + threadIdx.x;
    if (e < EE) {
        int p = atomicAdd(&cursor[idx_i[e]], 1);
        eids[p] = e;
    }
}

// ---------------------------------------------------------------------------
// geometry per edge: dir[E,3], cut[E], rbf[E,R]
__global__ __launch_bounds__(256) void k_geom(const float* __restrict__ pos,
                                              const int* __restrict__ idx_i,
                                              const int* __restrict__ idx_j,
                                              float* __restrict__ dir,
                                              float* __restrict__ cutb,
                                              float* __restrict__ rbf) {
    int e = blockIdx.x * 256 + threadIdx.x;
    if (e >= EE) return;
    int i = idx_i[e], j = idx_j[e];
    float dx = pos[j * 3 + 0] - pos[i * 3 + 0];
    float dy = pos[j * 3 + 1] - pos[i * 3 + 1];
    float dz = pos[j * 3 + 2] - pos[i * 3 + 2];
    float sq = dx * dx + dy * dy + dz * dz;
    float dist = sq > 0.f ? sqrtf(sq) : 0.f;
    float inv = dist > 0.f ? 1.f / dist : 0.f;
    dir[e * 3 + 0] = dx * inv;
    dir[e * 3 + 1] = dy * inv;
    dir[e * 3 + 2] = dz * inv;
    cutb[e] = (dist < CUTOFF) ? 0.5f * (cosf(PI_F * dist / CUTOFF) + 1.f) : 0.f;
    float b = PI_F * dist / CUTOFF;
#pragma unroll
    for (int r = 0; r < RR; r++)
        rbf[e * RR + r] = sinf((float)(r + 1) * b) * inv;
}

// ---------------------------------------------------------------------------
// Fused message MLP: phi = (silu(s@w1+b1))@w2 + b2    [N,384]
// block: 256 threads, 32 rows; h kept in LDS.
__global__ __launch_bounds__(256) void k_msg(const float* __restrict__ sfeat,
                                             const float* __restrict__ w1,
                                             const float* __restrict__ b1,
                                             const float* __restrict__ w2,
                                             const float* __restrict__ b2,
                                             float* __restrict__ phi) {
    __shared__ float As[32 * 129];
    __shared__ float Hs[32 * 129];
    const int tid = threadIdx.x;
    const int row0 = blockIdx.x * 32;
    for (int idx = tid; idx < 32 * 128; idx += 256) {
        int r = idx >> 7, k = idx & 127;
        int row = row0 + r;
        As[r * 129 + k] = (row < NN) ? sfeat[row * FF + k] : 0.f;
    }
    __syncthreads();
    const int r = tid >> 3;
    const int c0 = (tid & 7) * 16;
    {
        float acc[16];
#pragma unroll
        for (int j = 0; j < 16; j++) acc[j] = b1[c0 + j];
        for (int k = 0; k < 128; k++) {
            float a = As[r * 129 + k];
            const float4* w4 = reinterpret_cast<const float4*>(w1 + k * FF + c0);
            fma16(acc, a, w4[0], w4[1], w4[2], w4[3]);
        }
#pragma unroll
        for (int j = 0; j < 16; j++) {
            float x = acc[j];
            Hs[r * 129 + c0 + j] = x / (1.f + expf(-x));
        }
    }
    __syncthreads();
    const int row = row0 + r;
#pragma unroll
    for (int ct = 0; ct < 3; ct++) {
        float acc[16];
#pragma unroll
        for (int j = 0; j < 16; j++) acc[j] = b2[ct * 128 + c0 + j];
        for (int k = 0; k < 128; k++) {
            float a = Hs[r * 129 + k];
            const float4* w4 = reinterpret_cast<const float4*>(w2 + (size_t)k * F3 + ct * 128 + c0);
            fma16(acc, a, w4[0], w4[1], w4[2], w4[3]);
        }
        if (row < NN) {
            float* out = phi + (size_t)row * F3 + ct * 128 + c0;
#pragma unroll
            for (int j = 0; j < 16; j++) out[j] = acc[j];
        }
    }
}

// ---------------------------------------------------------------------------
// Node-centric edge accumulation (no atomics). One wave per node, CSR edges.
//   per edge e=(i<-j): W_c = cut*(rbf_b[c]+rbf@rbf_w); pw = phi[j,c]*W_c
//   split cols: 0:128 vv | 128:256 ss | 256:384 vs
//   sfeat[i] += Σ ss ; vnew[i,d,f] = vold[i,d,f] + Σ (vold[j,d,f]*vv + vs*dir_d)
__global__ __launch_bounds__(512) void k_edge_node(const int* __restrict__ rowstart,
                                                   const int* __restrict__ eids,
                                                   const int* __restrict__ idx_j,
                                                   const float* __restrict__ dir,
                                                   const float* __restrict__ cutb,
                                                   const float* __restrict__ rbf,
                                                   const float* __restrict__ phi,
                                                   const float* __restrict__ vold,
                                                   const float* __restrict__ rbf_w,
                                                   const float* __restrict__ rbf_b,
                                                   float* __restrict__ sfeat,
                                                   float* __restrict__ vnew) {
    __shared__ float sW[RR * F3 + F3];   // 8064 floats = 31.5 KB
    for (int idx = threadIdx.x; idx < RR * F3; idx += 512) sW[idx] = rbf_w[idx];
    for (int idx = threadIdx.x; idx < F3; idx += 512) sW[RR * F3 + idx] = rbf_b[idx];
    __syncthreads();
    const int wave = threadIdx.x >> 6, lane = threadIdx.x & 63;
    const int n = blockIdx.x * 8 + wave;       // grid covers exactly NN
    float as0 = 0.f, as1 = 0.f;
    float ad00 = 0.f, ad01 = 0.f, ad10 = 0.f, ad11 = 0.f, ad20 = 0.f, ad21 = 0.f;
    const int t1 = rowstart[n + 1];
    for (int t = rowstart[n]; t < t1; ++t) {
        const int e = eids[t];
        const float c = cutb[e];
        if (c == 0.f) continue;                // wave-uniform
        const int j = idx_j[e];
        const float d0 = dir[e * 3 + 0], d1 = dir[e * 3 + 1], d2 = dir[e * 3 + 2];
        float rb[RR];
#pragma unroll
        for (int rr = 0; rr < RR; rr++) rb[rr] = rbf[e * RR + rr];  // broadcast
        float pw[6];
#pragma unroll
        for (int cb = 0; cb < 6; cb++) {
            const int col = cb * 64 + lane;
            float w = sW[RR * F3 + col];
#pragma unroll
            for (int rr = 0; rr < RR; rr++) w += rb[rr] * sW[rr * F3 + col];
            pw[cb] = phi[(size_t)j * F3 + col] * (w * c);
        }
        as0 += pw[2]; as1 += pw[3];
        const float vj00 = vold[(size_t)j * F3 + 0 * FF + lane];
        const float vj01 = vold[(size_t)j * F3 + 0 * FF + 64 + lane];
        const float vj10 = vold[(size_t)j * F3 + 1 * FF + lane];
        const float vj11 = vold[(size_t)j * F3 + 1 * FF + 64 + lane];
        const float vj20 = vold[(size_t)j * F3 + 2 * FF + lane];
        const float vj21 = vold[(size_t)j * F3 + 2 * FF + 64 + lane];
        ad00 += vj00 * pw[0] + pw[4] * d0;  ad01 += vj01 * pw[1] + pw[5] * d0;
        ad10 += vj10 * pw[0] + pw[4] * d1;  ad11 += vj11 * pw[1] + pw[5] * d1;
        ad20 += vj20 * pw[0] + pw[4] * d2;  ad21 += vj21 * pw[1] + pw[5] * d2;
    }
    sfeat[n * FF + lane]      += as0;          // node owned by this wave: no atomics
    sfeat[n * FF + 64 + lane] += as1;
    vnew[(size_t)n * F3 + 0 * FF + lane]      = vold[(size_t)n * F3 + 0 * FF + lane]      + ad00;
    vnew[(size_t)n * F3 + 0 * FF + 64 + lane] = vold[(size_t)n * F3 + 0 * FF + 64 + lane] + ad01;
    vnew[(size_t)n * F3 + 1 * FF + lane]      = vold[(size_t)n * F3 + 1 * FF + lane]      + ad10;
    vnew[(size_t)n * F3 + 1 * FF + 64 + lane] = vold[(size_t)n * F3 + 1 * FF + 64 + lane] + ad11;
    vnew[(size_t)n * F3 + 2 * FF + lane]      = vold[(size_t)n * F3 + 2 * FF + lane]      + ad20;
    vnew[(size_t)n * F3 + 2 * FF + 64 + lane] = vold[(size_t)n * F3 + 2 * FF + 64 + lane] + ad21;
}

// ---------------------------------------------------------------------------
// Dual GEMM sharing the A tile: CU = A@WU, CV = A@WV   (A: [M,128], W: [128,128])
// block: 256 threads, 64 rows (2 rows/thread)
__global__ __launch_bounds__(256) void k_uv(const float* __restrict__ A,
                                            const float* __restrict__ WU,
                                            const float* __restrict__ WV,
                                            float* __restrict__ CU,
                                            float* __restrict__ CV, int M) {
    __shared__ float As[64 * 129];
    const int tid = threadIdx.x;
    const int row0 = blockIdx.x * 64;
    for (int idx = tid; idx < 64 * 128; idx += 256) {
        int r = idx >> 7, k = idx & 127;
        int row = row0 + r;
        As[r * 129 + k] = (row < M) ? A[(size_t)row * 128 + k] : 0.f;
    }
    __syncthreads();
    const int r = tid >> 3;
    const int c0 = (tid & 7) * 16;
    float aU[2][16] = {}, aV[2][16] = {};
    for (int k = 0; k < 128; k++) {
        const float4* u4 = reinterpret_cast<const float4*>(WU + k * 128 + c0);
        const float4* v4 = reinterpret_cast<const float4*>(WV + k * 128 + c0);
        float4 u0 = u4[0], u1 = u4[1], u2 = u4[2], u3 = u4[3];
        float4 v0 = v4[0], v1 = v4[1], v2 = v4[2], v3 = v4[3];
        float a0 = As[r * 129 + k];
        float a1 = As[(r + 32) * 129 + k];
        fma16(aU[0], a0, u0, u1, u2, u3);
        fma16(aU[1], a1, u0, u1, u2, u3);
        fma16(aV[0], a0, v0, v1, v2, v3);
        fma16(aV[1], a1, v0, v1, v2, v3);
    }
#pragma unroll
    for (int p = 0; p < 2; p++) {
        int row = row0 + r + 32 * p;
        if (row < M) {
            float* cu = CU + (size_t)row * 128 + c0;
            float* cv = CV + (size_t)row * 128 + c0;
#pragma unroll
            for (int j = 0; j < 16; j++) { cu[j] = aU[p][j]; cv[j] = aV[p][j]; }
        }
    }
}

// ---------------------------------------------------------------------------
// Generic fp32 MLP (kept for upd layer-1, K=256, concat A): C = act(A_cat@W + b)
template <int KTOT, int ROWS, bool SILU>
__global__ __launch_bounds__(256) void k_mlp(const float* __restrict__ A, int KA,
                                             const float* __restrict__ A2,
                                             const float* __restrict__ W,
                                             const float* __restrict__ bias,
                                             float* __restrict__ C, int M, int NOUT) {
    constexpr int RPT = ROWS / 32;
    __shared__ float As[ROWS * (KTOT + 1)];
    const int tid = threadIdx.x;
    const int row0 = blockIdx.x * ROWS;
    const int K2 = KTOT - KA;
    for (int idx = tid; idx < ROWS * KTOT; idx += 256) {
        int r = idx / KTOT, k = idx - r * KTOT;
        int row = row0 + r;
        float val = 0.f;
        if (row < M) val = (k < KA) ? A[row * KA + k] : A2[row * K2 + (k - KA)];
        As[r * (KTOT + 1) + k] = val;
    }
    __syncthreads();
    const int r = tid >> 3;
    const int c0 = blockIdx.y * 128 + (tid & 7) * 16;
    float acc[RPT][16];
#pragma unroll
    for (int p = 0; p < RPT; p++)
#pragma unroll
        for (int j = 0; j < 16; j++) acc[p][j] = bias ? bias[c0 + j] : 0.f;
    for (int k = 0; k < KTOT; k++) {
        const float4* w4 = reinterpret_cast<const float4*>(W + (size_t)k * NOUT + c0);
        float4 w0 = w4[0], w1 = w4[1], w2 = w4[2], w3 = w4[3];
#pragma unroll
        for (int p = 0; p < RPT; p++)
            fma16(acc[p], As[(r + 32 * p) * (KTOT + 1) + k], w0, w1, w2, w3);
    }
#pragma unroll
    for (int p = 0; p < RPT; p++) {
        int row = row0 + r + 32 * p;
        if (row < M) {
            float* crow = C + (size_t)row * NOUT + c0;
#pragma unroll
            for (int j = 0; j < 16; j++) {
                float x = acc[p][j];
                if (SILU) x = x / (1.f + expf(-x));
                crow[j] = x;
            }
        }
    }
}

// ---------------------------------------------------------------------------
// per (n,g): vnorm = safe_norm(Vv[n,:,g]), dot = <Uv,Vv>
__global__ __launch_bounds__(256) void k_normdot(const float* __restrict__ Uv,
                                                 const float* __restrict__ Vv,
                                                 float* __restrict__ vnorm,
                                                 float* __restrict__ dotb) {
    int idx = blockIdx.x * 256 + threadIdx.x;
    if (idx >= NN * FF) return;
    int n = idx >> 7, g = idx & 127;
    const float* uv = Uv + (size_t)n * F3 + g;
    const float* vv = Vv + (size_t)n * F3 + g;
    float u0 = uv[0], u1 = uv[FF], u2 = uv[2 * FF];
    float w0 = vv[0], w1 = vv[FF], w2 = vv[2 * FF];
    float sq = w0 * w0 + w1 * w1 + w2 * w2;
    vnorm[idx] = sq > 0.f ? sqrtf(sq) : 0.f;
    dotb[idx] = u0 * w0 + u1 * w1 + u2 * w2;
}

// ---------------------------------------------------------------------------
// Fused update layer-2 + gating: a = h@w2+b2 (all 384 cols per block), then
//   v[n,d,g] += Uv[n,d,g]*a_vv ; sfeat[n,g] += a_ss + a_sv*dot
__global__ __launch_bounds__(256) void k_upd2(const float* __restrict__ h,
                                              const float* __restrict__ w2,
                                              const float* __restrict__ b2,
                                              const float* __restrict__ Uv,
                                              const float* __restrict__ dotb,
                                              float* __restrict__ v,
                                              float* __restrict__ sfeat) {
    __shared__ float As[32 * 129];
    const int tid = threadIdx.x;
    const int row0 = blockIdx.x * 32;
    for (int idx = tid; idx < 32 * 128; idx += 256) {
        int r = idx >> 7, k = idx & 127;
        int row = row0 + r;
        As[r * 129 + k] = (row < NN) ? h[row * FF + k] : 0.f;
    }
    __syncthreads();
    const int r = tid >> 3;
    const int c0 = (tid & 7) * 16;
    float acc[3][16];
#pragma unroll
    for (int ct = 0; ct < 3; ct++) {
#pragma unroll
        for (int j = 0; j < 16; j++) acc[ct][j] = b2[ct * 128 + c0 + j];
        for (int k = 0; k < 128; k++) {
            float a = As[r * 129 + k];
            const float4* w4 = reinterpret_cast<const float4*>(w2 + (size_t)k * F3 + ct * 128 + c0);
            fma16(acc[ct], a, w4[0], w4[1], w4[2], w4[3]);
        }
    }
    const int row = row0 + r;
    if (row < NN) {
#pragma unroll
        for (int j = 0; j < 16; j++) {
            const int g = c0 + j;
            const float avv = acc[0][j], asv = acc[1][j], ass = acc[2][j];
            sfeat[row * FF + g] += ass + asv * dotb[row * FF + g];
#pragma unroll
            for (int d = 0; d < 3; d++)
                v[(size_t)row * F3 + d * FF + g] += Uv[(size_t)row * F3 + d * FF + g] * avv;
        }
    }
}

// ---------------------------------------------------------------------------
// transpose internal v[N,3,F] -> output vfeat[N,F,3]
__global__ __launch_bounds__(256) void k_outv(const float* __restrict__ v,
                                              float* __restrict__ outv) {
    int idx = blockIdx.x * 256 + threadIdx.x;
    if (idx >= NN * FF * 3) return;
    int n = idx / F3;
    int rem = idx - n * F3;
    int f = rem / 3;
    int d = rem - f * 3;
    outv[idx] = v[n * F3 + d * FF + f];
}

// ---------------------------------------------------------------------------
extern "C" void kernel_launch(void* const* d_in, const int* in_sizes, int n_in,
                              void* d_out, int out_size, void* d_ws, size_t ws_size,
                              hipStream_t stream) {
    const int*   z      = (const int*)d_in[0];
    const float* pos    = (const float*)d_in[1];
    const int*   idx_i  = (const int*)d_in[2];
    const int*   idx_j  = (const int*)d_in[3];
    const float* emb    = (const float*)d_in[4];
    const float* msg_w1 = (const float*)d_in[5];
    const float* msg_b1 = (const float*)d_in[6];
    const float* msg_w2 = (const float*)d_in[7];
    const float* msg_b2 = (const float*)d_in[8];
    const float* rbf_w  = (const float*)d_in[9];
    const float* rbf_b  = (const float*)d_in[10];
    const float* upd_U  = (const float*)d_in[11];
    const float* upd_V  = (const float*)d_in[12];
    const float* upd_w1 = (const float*)d_in[13];
    const float* upd_b1 = (const float*)d_in[14];
    const float* upd_w2 = (const float*)d_in[15];
    const float* upd_b2 = (const float*)d_in[16];

    float* sfeat = (float*)d_out;            // [N,F]
    float* outv  = sfeat + NN * FF;          // [N,F,3]

    float* ws    = (float*)d_ws;
    float* va    = ws;                       // [N,3,F] ping
    float* vb    = va + NN * F3;             // [N,3,F] pong
    float* phi   = vb + NN * F3;             // [N,3F]
    float* h     = phi + NN * F3;            // [N,F]
    float* Uvb   = h + NN * FF;              // [N,3,F]
    float* Vvb   = Uvb + NN * F3;            // [N,3,F]
    float* vnorm = Vvb + NN * F3;            // [N,F]
    float* dotb  = vnorm + NN * FF;          // [N,F]
    float* rbf   = dotb + NN * FF;           // [E,R]
    float* cutb  = rbf + EE * RR;            // [E]
    float* dirb  = cutb + EE;                // [E,3]
    int*   ib        = (int*)(dirb + EE * 3);
    int*   deg       = ib;                   // [N]
    int*   rowstart  = deg + NN;             // [N+1]
    int*   cursor    = rowstart + NN + 1;    // [N]
    int*   eids      = cursor + NN;          // [E]

    const dim3 blk(256);
    k_init<<<dim3((NN * 3 * FF) / 256), blk, 0, stream>>>(z, emb, sfeat, va, deg);
    k_count<<<dim3((EE + 255) / 256), blk, 0, stream>>>(idx_i, deg);
    k_scan<<<dim3(1), dim3(1024), 0, stream>>>(deg, rowstart, cursor);
    k_fill<<<dim3((EE + 255) / 256), blk, 0, stream>>>(idx_i, cursor, eids);
    k_geom<<<dim3((EE + 255) / 256), blk, 0, stream>>>(pos, idx_i, idx_j, dirb, cutb, rbf);

    float* vcur = va;
    float* vnxt = vb;
    const int gM_N32  = (NN + 31) / 32;      // 313
    const int gM_3N64 = (3 * NN + 63) / 64;  // 469

    for (int l = 0; l < LL; l++) {
        const float* mw1 = msg_w1 + l * FF * FF;
        const float* mb1 = msg_b1 + l * FF;
        const float* mw2 = msg_w2 + l * FF * F3;
        const float* mb2 = msg_b2 + l * F3;
        const float* rw  = rbf_w + l * RR * F3;
        const float* rb  = rbf_b + l * F3;
        const float* uU  = upd_U + l * FF * FF;
        const float* uV  = upd_V + l * FF * FF;
        const float* uw1 = upd_w1 + l * 2 * FF * FF;
        const float* ub1 = upd_b1 + l * FF;
        const float* uw2 = upd_w2 + l * FF * F3;
        const float* ub2 = upd_b2 + l * F3;

        // phi = (silu(s@w1+b1))@w2+b2
        k_msg<<<dim3(gM_N32), blk, 0, stream>>>(sfeat, mw1, mb1, mw2, mb2, phi);

        // node-centric message aggregation: sfeat += ..., vnxt = vcur + dv
        k_edge_node<<<dim3(NN / 8), dim3(512), 0, stream>>>(rowstart, eids, idx_j, dirb,
                                                            cutb, rbf, phi, vcur, rw, rb,
                                                            sfeat, vnxt);

        // Uv/Vv dual GEMM on vnxt
        k_uv<<<dim3(gM_3N64), blk, 0, stream>>>(vnxt, uU, uV, Uvb, Vvb, 3 * NN);
        k_normdot<<<dim3((NN * FF) / 256), blk, 0, stream>>>(Uvb, Vvb, vnorm, dotb);

        // h = silu([vnorm|sfeat]@w1+b1)
        k_mlp<256, 32, true><<<dim3(gM_N32, 1), blk, 0, stream>>>(vnorm, 128, sfeat, uw1, ub1, h, NN, 128);

        // a = h@w2+b2 fused with gating epilogue (updates vnxt, sfeat)
        k_upd2<<<dim3(gM_N32), blk, 0, stream>>>(h, uw2, ub2, Uvb, dotb, vnxt, sfeat);

        // ping-pong
        float* tmp = vcur; vcur = vnxt; vnxt = tmp;
    }

    k_outv<<<dim3((NN * FF * 3 + 255) / 256), blk, 0, stream>>>(vcur, outv);
}